// Round 10
// baseline (105.937 us; speedup 1.0000x reference)
//
#include <hip/hip_runtime.h>
#include <hip/hip_bf16.h>

// SimCLR loss, N=8192, D=128, T=0.1.
//  k1 (prep):  row L2-normalize fp32 -> bf16 znb (unscaled) + znbs (x 10*log2e);
//              selfe[i] = exp2(MFMA-matched self dot); poslog[i] = 10*fp32 dot.
//  k2 (sim):   SYMMETRY-HALVED: only upper-triangle 256x256 tiles (I<=J).
//              Block (I,J): row-sums of exp2(mfma(znbs_I, znb_J)) -> slot J of
//              rows RB_I; col-sums (cross-wave LDS reduce) -> slot I of rows
//              RB_J. Slot coverage per row-tile T: {J>T} u {T} u {K<T} = all 32,
//              exactly once, no atomics. Uses sim(i,j)~sim(j,i) (bf16 rounding
//              asymmetry ~2.5e-3 relative/element, ~4e-7 in the mean loss).
//              Structure = round-7/8 A/B winner: 8 waves x 512 thr, 32 rows/wave,
//              afrag 32 VGPRs (demand ~82 <= allocator's 84 budget -> no spills;
//              demand-132 variant spilled 104KB/block and ran 4.5x slower).
//              B staged via global_load_lds (linear dest, inverse-swizzled src),
//              2x16KB dbuf, 1 barrier/chunk.
//  k3a/k3b:    denom = sum(partials) - selfe; loss = mean(log(denom) - poslog).
//
// Fixed overhead: ~42 us of every timed window is the harness's 256 MB d_ws
// poison fill draining on the stream (fillBufferAligned @ ~80% HBM peak).
// (Round 9: acquisition timeout — experiment resubmitted unchanged.)

constexpr int N = 8192;
constexpr int D = 128;
constexpr float SCALE = 14.4269504088896341f;  // 10 * log2(e)

typedef short bf16x8 __attribute__((ext_vector_type(8)));
typedef float f32x4 __attribute__((ext_vector_type(4)));

#if __has_builtin(__builtin_amdgcn_exp2f)
#define EXP2(x) __builtin_amdgcn_exp2f(x)
#else
#define EXP2(x) exp2f(x)
#endif

static __device__ __forceinline__ unsigned short f2bf(float x) {
  __hip_bfloat16 h = __float2bfloat16(x);  // RTNE
  unsigned short u;
  __builtin_memcpy(&u, &h, 2);
  return u;
}
static __device__ __forceinline__ float bf2f(unsigned short u) {
  unsigned int x = ((unsigned int)u) << 16;
  float f;
  __builtin_memcpy(&f, &x, 4);
  return f;
}
static __device__ __forceinline__ void gload_lds16(const void* g, void* l) {
  __builtin_amdgcn_global_load_lds(
      (const __attribute__((address_space(1))) unsigned int*)g,
      (__attribute__((address_space(3))) unsigned int*)l, 16, 0, 0);
}

// ------------- kernel 1: normalize + bf16 convert + self-term + pos-term -------------
__global__ __launch_bounds__(256) void simclr_prep(const float* __restrict__ z,
                                                   unsigned short* __restrict__ znb,
                                                   unsigned short* __restrict__ znbs,
                                                   float* __restrict__ selfe,
                                                   float* __restrict__ poslog) {
  const int row = blockIdx.x * 4 + (threadIdx.x >> 6);
  const int par = row ^ (N / 2);
  const int lane = threadIdx.x & 63;
  const float2 v = *(const float2*)(z + row * D + lane * 2);
  const float2 b = *(const float2*)(z + par * D + lane * 2);
  float ss = v.x * v.x + v.y * v.y;
  float sb = b.x * b.x + b.y * b.y;
  float dp = v.x * b.x + v.y * b.y;
#pragma unroll
  for (int m = 1; m < 64; m <<= 1) {
    ss += __shfl_xor(ss, m);
    sb += __shfl_xor(sb, m);
    dp += __shfl_xor(dp, m);
  }
  const float rn = rsqrtf(ss);
  const float a0 = v.x * rn, a1 = v.y * rn;
  const unsigned short u0 = f2bf(a0), u1 = f2bf(a1);
  const unsigned short s0 = f2bf(a0 * SCALE), s1 = f2bf(a1 * SCALE);
  *(unsigned int*)(znb + row * D + lane * 2) = (unsigned int)u0 | ((unsigned int)u1 << 16);
  *(unsigned int*)(znbs + row * D + lane * 2) = (unsigned int)s0 | ((unsigned int)s1 << 16);
  // self dot with exactly the MFMA's bf16 products (fp32 sum; order-only mismatch ~1e-5)
  float sa = bf2f(s0) * bf2f(u0) + bf2f(s1) * bf2f(u1);
#pragma unroll
  for (int m = 1; m < 64; m <<= 1) sa += __shfl_xor(sa, m);
  if (lane == 0) {
    selfe[row] = EXP2(sa);
    poslog[row] = 10.0f * dp * rsqrtf(ss * sb);
  }
}

// ---------------- kernel 2: sim, upper-triangle tiles, 8-wave structure ----------------
// grid = 32*32 = 1024 blocks (J<I exit); block = 512 threads (8 waves).
// Wave w owns rows [RB + w*32, +32) of tile I; B staged from col-tile J.
__global__ __launch_bounds__(512)
__attribute__((amdgpu_waves_per_eu(4, 4)))
void simclr_sim(const unsigned short* __restrict__ znb,
                const unsigned short* __restrict__ znbs,
                float* __restrict__ partials) {
  const int bi = blockIdx.x;
  const int I = bi >> 5, J = bi & 31;
  if (J < I) return;  // upper triangle only

  __shared__ unsigned short lb[2][64 * 128];  // 2 x 16KB B-chunk, XOR-swizzled
  __shared__ float colacc[8][256];            // per-wave col partials (8KB)

  const int RB = I << 8;  // row-tile base
  const int CB = J << 8;  // col-tile base
  const int tid = threadIdx.x;
  const int lane = tid & 63;
  const int w = tid >> 6;  // 0..7
  const int l15 = lane & 15, l4 = lane >> 4;
  const bool offdiag = (I != J);

  // A layout (16x16x32): lane holds A[l&15][(l>>4)*8 + 0..7], k = s*32 + l4*8.
  bf16x8 afrag[2][4];
#pragma unroll
  for (int rt = 0; rt < 2; ++rt)
#pragma unroll
    for (int s = 0; s < 4; ++s)
      afrag[rt][s] =
          *(const bf16x8*)(znbs + (RB + w * 32 + rt * 16 + l15) * D + s * 32 + l4 * 8);

  float dpart[8];
#pragma unroll
  for (int k = 0; k < 8; ++k) dpart[k] = 0.f;

  // Stage chunk cc (64 B-rows = 16KB): 8 waves x 2 instrs, linear LDS dest,
  // inverse-swizzled global source (position sl holds global chunk sl^(rr&7)).
#define STAGE(buf_, cc_)                                                        \
  {                                                                             \
    _Pragma("unroll") for (int i = 0; i < 2; ++i) {                             \
      const int rr = (w * 2 + i) * 4 + l4;                                      \
      const unsigned short* g =                                                 \
          znb + (CB + (cc_) * 64 + rr) * D + ((l15 ^ (rr & 7)) << 3);           \
      gload_lds16(g, (char*)lb[buf_] + (w * 2 + i) * 1024);                     \
    }                                                                           \
  }

  STAGE(0, 0);
  __syncthreads();

  int buf = 0;
  for (int cc = 0; cc < 4; ++cc) {
    if (cc < 3) STAGE(buf ^ 1, cc + 1);
    const char* lbc = (const char*)lb[buf];
#pragma unroll
    for (int jt = 0; jt < 4; ++jt) {
      const int jr = jt * 16 + l15;
      const int swz = (jr & 7) << 4;
      // B layout: lane holds B[s*32 + l4*8 + 0..7][l15]
      bf16x8 bfrag[4];
#pragma unroll
      for (int s = 0; s < 4; ++s)
        bfrag[s] = *(const bf16x8*)(lbc + jr * 256 + ((s * 64 + l4 * 16) ^ swz));
      f32x4 acc[2];
#pragma unroll
      for (int rt = 0; rt < 2; ++rt) acc[rt] = f32x4{0.f, 0.f, 0.f, 0.f};
#pragma unroll
      for (int s = 0; s < 4; ++s)
#pragma unroll
        for (int rt = 0; rt < 2; ++rt)
          acc[rt] = __builtin_amdgcn_mfma_f32_16x16x32_bf16(afrag[rt][s], bfrag[s],
                                                            acc[rt], 0, 0, 0);
      // acc = 10*log2(e)*dot (A pre-scaled): exp2; accumulate row AND col paths
      float s8 = 0.f;
#pragma unroll
      for (int rt = 0; rt < 2; ++rt)
#pragma unroll
        for (int r = 0; r < 4; ++r) {
          const float e = EXP2(acc[rt][r]);
          dpart[rt * 4 + r] += e;
          s8 += e;
        }
      if (offdiag) {
        // col partial over this wave's 32 rows: reduce across l4 groups
        s8 += __shfl_xor(s8, 16);
        s8 += __shfl_xor(s8, 32);
        if (l4 == 0) colacc[w][cc * 64 + jt * 16 + l15] = s8;
      }
    }
    __syncthreads();  // chunk ready + buf reads drained (+ colacc visible at end)
    buf ^= 1;
  }
#undef STAGE

  // row path: reduce across the 16 column-lanes; slot J of row-tile I
#pragma unroll
  for (int m = 1; m < 16; m <<= 1)
#pragma unroll
    for (int k = 0; k < 8; ++k) dpart[k] += __shfl_xor(dpart[k], m);

  if (l15 == 0) {
    // C/D layout: row = l4*4 + r within each 16-row tile
    float* pp = partials + J * N + RB + w * 32 + l4 * 4;
#pragma unroll
    for (int rt = 0; rt < 2; ++rt)
#pragma unroll
      for (int r = 0; r < 4; ++r) pp[rt * 16 + r] = dpart[rt * 4 + r];
  }

  // col path: sum the 8 per-wave partials; slot I of row-tile J
  if (offdiag && tid < 256) {
    float cs = 0.f;
#pragma unroll
    for (int w2 = 0; w2 < 8; ++w2) cs += colacc[w2][tid];
    partials[I * N + CB + tid] = cs;
  }
}

// ---------------- kernel 3a: per-row loss, per-block partial sums ----------------
__global__ __launch_bounds__(256) void simclr_rowloss(const float* __restrict__ partials,
                                                      const float* __restrict__ selfe,
                                                      const float* __restrict__ poslog,
                                                      float* __restrict__ bsum) {
  const int tid = threadIdx.x;
  const int i = blockIdx.x * 256 + tid;
  float d = -selfe[i];
#pragma unroll
  for (int cb = 0; cb < 32; ++cb) d += partials[cb * N + i];
  float s = logf(d) - poslog[i];
#pragma unroll
  for (int m = 1; m < 64; m <<= 1) s += __shfl_xor(s, m);
  __shared__ float acc[4];
  if ((tid & 63) == 0) acc[tid >> 6] = s;
  __syncthreads();
  if (tid == 0) bsum[blockIdx.x] = acc[0] + acc[1] + acc[2] + acc[3];
}

// ---------------- kernel 3b: final scalar ----------------
__global__ __launch_bounds__(64) void simclr_final(const float* __restrict__ bsum,
                                                   float* __restrict__ out) {
  const int tid = threadIdx.x;
  float s = (tid < 32) ? bsum[tid] : 0.f;
#pragma unroll
  for (int m = 1; m < 64; m <<= 1) s += __shfl_xor(s, m);
  if (tid == 0) out[0] = s * (1.0f / N);
}

extern "C" void kernel_launch(void* const* d_in, const int* in_sizes, int n_in,
                              void* d_out, int out_size, void* d_ws, size_t ws_size,
                              hipStream_t stream) {
  const float* z = (const float*)d_in[0];
  float* out = (float*)d_out;

  float* partials = (float*)d_ws;                      // 32*N
  float* selfe = partials + 32 * N;                    // N
  float* poslog = selfe + N;                           // N
  float* bsum = poslog + N;                            // 32 (pad to 64)
  unsigned short* znb = (unsigned short*)(bsum + 64);  // N*D bf16 (16B-aligned)
  unsigned short* znbs = znb + N * D;                  // N*D bf16

  simclr_prep<<<N / 4, 256, 0, stream>>>(z, znb, znbs, selfe, poslog);
  simclr_sim<<<32 * 32, 512, 0, stream>>>(znb, znbs, partials);
  simclr_rowloss<<<N / 256, 256, 0, stream>>>(partials, selfe, poslog, bsum);
  simclr_final<<<1, 64, 0, stream>>>(bsum, out);
}

// Round 11
// 93.418 us; speedup vs baseline: 1.1340x; 1.1340x over previous
//
#include <hip/hip_runtime.h>
#include <hip/hip_bf16.h>

// SimCLR loss, N=8192, D=128, T=0.1.
//  k1 (prep):  row L2-normalize fp32 -> bf16 znb (unscaled) + znbs (x 10*log2e);
//              selfe[i] = exp2(MFMA-matched self dot); poslog[i] = 10*fp32 dot;
//              + zero partials[128][N] (2 stores/thread, no extra dispatch).
//  k2 (sim):   SYMMETRY-HALVED, 128x128 tiles, upper triangle I<=J (64x64 grid,
//              J<I exits). Row-sums -> slot J (plain stores). Col-sums (via
//              sim(i,j)=sim(j,i)) -> slot 64+I by fire-and-forget atomicAdd:
//              ZERO extra VGPRs/LDS vs the proven structure. Coverage of target
//              tile T: row slots [T,64) + col slots {64+I, I<T}, rest zero.
//  k3a/k3b:    denom = sum(128 slots) - selfe; loss = mean(log(denom) - poslog).
//
// Register-budget ledger (the round 3-10 saga): allocator picks its own VGPR
// budget by block shape: 256thr -> 84 (3x measured), 512thr/40KB -> 64 (R10,
// spilled 92KB/block, 44.6us). waves_per_eu/launch_bounds hints IGNORED.
// => use 256-thr blocks and keep demand ~80 <= 84: afrag 32 + bfrag 16 +
// acc 8 + dpart 8 + addressing ~16. Col path costs 0 regs (atomics).
//
// Fixed overhead: ~42 us of every timed window is the harness's 256 MB d_ws
// poison fill draining on the stream (fillBufferAligned @ ~80% HBM peak).

constexpr int N = 8192;
constexpr int D = 128;
constexpr float SCALE = 14.4269504088896341f;  // 10 * log2(e)

typedef short bf16x8 __attribute__((ext_vector_type(8)));
typedef float f32x4 __attribute__((ext_vector_type(4)));

#if __has_builtin(__builtin_amdgcn_exp2f)
#define EXP2(x) __builtin_amdgcn_exp2f(x)
#else
#define EXP2(x) exp2f(x)
#endif

static __device__ __forceinline__ unsigned short f2bf(float x) {
  __hip_bfloat16 h = __float2bfloat16(x);  // RTNE
  unsigned short u;
  __builtin_memcpy(&u, &h, 2);
  return u;
}
static __device__ __forceinline__ float bf2f(unsigned short u) {
  unsigned int x = ((unsigned int)u) << 16;
  float f;
  __builtin_memcpy(&f, &x, 4);
  return f;
}
static __device__ __forceinline__ void gload_lds16(const void* g, void* l) {
  __builtin_amdgcn_global_load_lds(
      (const __attribute__((address_space(1))) unsigned int*)g,
      (__attribute__((address_space(3))) unsigned int*)l, 16, 0, 0);
}

// ------------- kernel 1: normalize + bf16 + self/pos terms + zero partials -------------
__global__ __launch_bounds__(256) void simclr_prep(const float* __restrict__ z,
                                                   unsigned short* __restrict__ znb,
                                                   unsigned short* __restrict__ znbs,
                                                   float* __restrict__ selfe,
                                                   float* __restrict__ poslog,
                                                   float* __restrict__ partials) {
  // zero the 128*N partials (grid 2048*256 = 524288 threads, 2 each)
  const int gid = blockIdx.x * 256 + threadIdx.x;
  partials[gid] = 0.f;
  partials[gid + 524288] = 0.f;

  const int row = blockIdx.x * 4 + (threadIdx.x >> 6);
  const int par = row ^ (N / 2);
  const int lane = threadIdx.x & 63;
  const float2 v = *(const float2*)(z + row * D + lane * 2);
  const float2 b = *(const float2*)(z + par * D + lane * 2);
  float ss = v.x * v.x + v.y * v.y;
  float sb = b.x * b.x + b.y * b.y;
  float dp = v.x * b.x + v.y * b.y;
#pragma unroll
  for (int m = 1; m < 64; m <<= 1) {
    ss += __shfl_xor(ss, m);
    sb += __shfl_xor(sb, m);
    dp += __shfl_xor(dp, m);
  }
  const float rn = rsqrtf(ss);
  const float a0 = v.x * rn, a1 = v.y * rn;
  const unsigned short u0 = f2bf(a0), u1 = f2bf(a1);
  const unsigned short s0 = f2bf(a0 * SCALE), s1 = f2bf(a1 * SCALE);
  *(unsigned int*)(znb + row * D + lane * 2) = (unsigned int)u0 | ((unsigned int)u1 << 16);
  *(unsigned int*)(znbs + row * D + lane * 2) = (unsigned int)s0 | ((unsigned int)s1 << 16);
  // self dot with exactly the MFMA's bf16 products (fp32 sum; order-only mismatch ~1e-5)
  float sa = bf2f(s0) * bf2f(u0) + bf2f(s1) * bf2f(u1);
#pragma unroll
  for (int m = 1; m < 64; m <<= 1) sa += __shfl_xor(sa, m);
  if (lane == 0) {
    selfe[row] = EXP2(sa);
    poslog[row] = 10.0f * dp * rsqrtf(ss * sb);
  }
}

// ---------------- kernel 2: sim, 128x128 upper-triangle tiles, 4 waves ----------------
// grid = 64*64 = 4096 blocks (J<I exit); block = 256 threads.
// Wave w owns rows [RB + w*32, +32); B-cols staged in 64-row chunks (16KB), dbuf.
__global__ __launch_bounds__(256)
void simclr_sim(const unsigned short* __restrict__ znb,
                const unsigned short* __restrict__ znbs,
                float* __restrict__ partials) {
  const int bi = blockIdx.x;
  const int I = bi >> 6, J = bi & 63;
  if (J < I) return;  // upper triangle only

  __shared__ unsigned short lb[2][64 * 128];  // 2 x 16KB, row = 256B, XOR-swizzled

  const int RB = I << 7;  // row-tile base (x128)
  const int CB = J << 7;  // col-tile base (x128)
  const int tid = threadIdx.x;
  const int lane = tid & 63;
  const int w = tid >> 6;  // 0..3
  const int l15 = lane & 15, l4 = lane >> 4;
  const bool offdiag = (I != J);

  // A layout (16x16x32): lane holds A[l&15][(l>>4)*8 + 0..7], k = s*32 + l4*8.
  bf16x8 afrag[2][4];
#pragma unroll
  for (int rt = 0; rt < 2; ++rt)
#pragma unroll
    for (int s = 0; s < 4; ++s)
      afrag[rt][s] =
          *(const bf16x8*)(znbs + (RB + w * 32 + rt * 16 + l15) * D + s * 32 + l4 * 8);

  float dpart[8];
#pragma unroll
  for (int k = 0; k < 8; ++k) dpart[k] = 0.f;

  // Stage chunk cc (64 B-rows = 16KB): 4 waves x 4 instrs, linear LDS dest,
  // inverse-swizzled global source (position sl holds global chunk sl^(rr&7)).
#define STAGE(buf_, cc_)                                                        \
  {                                                                             \
    _Pragma("unroll") for (int i = 0; i < 4; ++i) {                             \
      const int rr = (w * 4 + i) * 4 + l4;                                      \
      const unsigned short* g =                                                 \
          znb + (CB + (cc_) * 64 + rr) * D + ((l15 ^ (rr & 7)) << 3);           \
      gload_lds16(g, (char*)lb[buf_] + (w * 4 + i) * 1024);                     \
    }                                                                           \
  }

  STAGE(0, 0);
  __syncthreads();

  int buf = 0;
#pragma unroll
  for (int cc = 0; cc < 2; ++cc) {
    if (cc < 1) STAGE(buf ^ 1, cc + 1);
    const char* lbc = (const char*)lb[buf];
#pragma unroll
    for (int jt = 0; jt < 4; ++jt) {
      const int jr = jt * 16 + l15;
      const int swz = (jr & 7) << 4;
      // B layout: lane holds B[s*32 + l4*8 + 0..7][l15]
      bf16x8 bfrag[4];
#pragma unroll
      for (int s = 0; s < 4; ++s)
        bfrag[s] = *(const bf16x8*)(lbc + jr * 256 + ((s * 64 + l4 * 16) ^ swz));
      f32x4 acc[2];
#pragma unroll
      for (int rt = 0; rt < 2; ++rt) acc[rt] = f32x4{0.f, 0.f, 0.f, 0.f};
#pragma unroll
      for (int s = 0; s < 4; ++s)
#pragma unroll
        for (int rt = 0; rt < 2; ++rt)
          acc[rt] = __builtin_amdgcn_mfma_f32_16x16x32_bf16(afrag[rt][s], bfrag[s],
                                                            acc[rt], 0, 0, 0);
      // acc = 10*log2(e)*dot (A pre-scaled): exp2; row path + col path
      float s8 = 0.f;
#pragma unroll
      for (int rt = 0; rt < 2; ++rt)
#pragma unroll
        for (int r = 0; r < 4; ++r) {
          const float e = EXP2(acc[rt][r]);
          dpart[rt * 4 + r] += e;
          s8 += e;
        }
      if (offdiag) {
        // wave's 32-row column sum: reduce over l4 groups (lane bits 4,5)
        s8 += __shfl_xor(s8, 16);
        s8 += __shfl_xor(s8, 32);
        if (l4 == 0)  // 16 lanes, consecutive cols: coalesced fire-and-forget
          atomicAdd(&partials[(64 + I) * N + CB + cc * 64 + jt * 16 + l15], s8);
      }
    }
    __syncthreads();
    buf ^= 1;
  }
#undef STAGE

  // row path: reduce across the 16 column-lanes; slot J of row-tile I
#pragma unroll
  for (int m = 1; m < 16; m <<= 1)
#pragma unroll
    for (int k = 0; k < 8; ++k) dpart[k] += __shfl_xor(dpart[k], m);

  if (l15 == 0) {
    // C/D layout: row = l4*4 + r within each 16-row tile
    float* pp = partials + J * N + RB + w * 32 + l4 * 4;
#pragma unroll
    for (int rt = 0; rt < 2; ++rt)
#pragma unroll
      for (int r = 0; r < 4; ++r) pp[rt * 16 + r] = dpart[rt * 4 + r];
  }
}

// ---------------- kernel 3a: per-row loss, per-block partial sums ----------------
__global__ __launch_bounds__(256) void simclr_rowloss(const float* __restrict__ partials,
                                                      const float* __restrict__ selfe,
                                                      const float* __restrict__ poslog,
                                                      float* __restrict__ bsum) {
  const int tid = threadIdx.x;
  const int i = blockIdx.x * 256 + tid;
  float d = -selfe[i];
#pragma unroll 16
  for (int cb = 0; cb < 128; ++cb) d += partials[cb * N + i];
  float s = logf(d) - poslog[i];
#pragma unroll
  for (int m = 1; m < 64; m <<= 1) s += __shfl_xor(s, m);
  __shared__ float acc[4];
  if ((tid & 63) == 0) acc[tid >> 6] = s;
  __syncthreads();
  if (tid == 0) bsum[blockIdx.x] = acc[0] + acc[1] + acc[2] + acc[3];
}

// ---------------- kernel 3b: final scalar ----------------
__global__ __launch_bounds__(64) void simclr_final(const float* __restrict__ bsum,
                                                   float* __restrict__ out) {
  const int tid = threadIdx.x;
  float s = (tid < 32) ? bsum[tid] : 0.f;
#pragma unroll
  for (int m = 1; m < 64; m <<= 1) s += __shfl_xor(s, m);
  if (tid == 0) out[0] = s * (1.0f / N);
}

extern "C" void kernel_launch(void* const* d_in, const int* in_sizes, int n_in,
                              void* d_out, int out_size, void* d_ws, size_t ws_size,
                              hipStream_t stream) {
  const float* z = (const float*)d_in[0];
  float* out = (float*)d_out;

  float* partials = (float*)d_ws;                      // 128*N (zeroed by prep)
  float* selfe = partials + 128 * N;                   // N
  float* poslog = selfe + N;                           // N
  float* bsum = poslog + N;                            // 32 (pad to 64)
  unsigned short* znb = (unsigned short*)(bsum + 64);  // N*D bf16 (16B-aligned)
  unsigned short* znbs = znb + N * D;                  // N*D bf16

  simclr_prep<<<N / 4, 256, 0, stream>>>(z, znb, znbs, selfe, poslog, partials);
  simclr_sim<<<64 * 64, 256, 0, stream>>>(znb, znbs, partials);
  simclr_rowloss<<<N / 256, 256, 0, stream>>>(partials, selfe, poslog, bsum);
  simclr_final<<<1, 64, 0, stream>>>(bsum, out);
}